// Round 3
// baseline (55994.086 us; speedup 1.0000x reference)
//
#include <hip/hip_runtime.h>
#include <math.h>

// ---------------- problem constants ----------------
#define BATCH 256
#define TLEN  519          // W + MAXLAG
#define WIN   512
#define HID   256
#define PRED  24
#define NS    100
#define NLAG  7
#define GROWS (BATCH * NS) // 25600 decoder rows

// ---------------- workspace layout (float/uint offsets) ----------------
#define OFF_SCALED 0
#define OFF_LOC    132864
#define OFF_SCALE  133120
#define OFF_WIH0   133376   // fp32 [f][j][q], f<7  (encoder lag weights)
#define OFF_WHH0H  140544   // half2 [p][j][q], p<128 (encoder)
#define OFF_WCAT1H 271616   // half2 [p][j][q], p<256 (encoder, ih1|hh1)
#define OFF_B0     533760   // fp32 combined b_ih0+b_hh0, [j][q]
#define OFF_B1     534784
#define OFF_BN0    535808   // fp32 bias by MFMA col n (layer0)
#define OFF_BN1    536832
#define OFF_F0     537856   // fp16 B-fragments layer0: 9 ks x 64 nt x 64 lane x 8
#define OFF_F1     685312   // fp16 B-fragments layer1: 16 ks x 64 nt x 64 lane x 8
#define OFF_EH0    947456   // encoder final states fp32 [b][j]
#define OFF_EC0    1012992
#define OFF_EH1    1078528
#define OFF_EC1    1144064
#define OFF_ACC    1209600  // sample accumulators [b][p]
#define WS_FLOATS  1215744  // 4.86 MB

// ---------------- helpers ----------------
typedef _Float16 h2_t  __attribute__((ext_vector_type(2)));
typedef _Float16 half8 __attribute__((ext_vector_type(8)));
typedef float    f32x4 __attribute__((ext_vector_type(4)));

__device__ __forceinline__ float sigm(float x) { return 1.0f / (1.0f + __expf(-x)); }
__device__ __forceinline__ float ftanh(float x) {
    float e = __expf(2.0f * x);
    return 1.0f - 2.0f / (e + 1.0f);
}
__device__ __forceinline__ float softplus(float x) {
    return (x > 15.0f) ? x : log1pf(__expf(x));
}
__device__ __forceinline__ void fma4(float4& a, const float4 w, const float x) {
    a.x = fmaf(w.x, x, a.x);
    a.y = fmaf(w.y, x, a.y);
    a.z = fmaf(w.z, x, a.z);
    a.w = fmaf(w.w, x, a.w);
}
__device__ __forceinline__ float dot2(unsigned int h, unsigned int w, float acc) {
    return __builtin_amdgcn_fdot2(__builtin_bit_cast(h2_t, h),
                                  __builtin_bit_cast(h2_t, w), acc, false);
}
__device__ __forceinline__ void dot2x4(float4& a, const unsigned int h, const uint4 w) {
    a.x = dot2(h, w.x, a.x);
    a.y = dot2(h, w.y, a.y);
    a.z = dot2(h, w.z, a.z);
    a.w = dot2(h, w.w, a.w);
}
__device__ __forceinline__ unsigned int packh2(float a, float b) {
    h2_t h;
    h.x = (_Float16)a;
    h.y = (_Float16)b;
    return __builtin_bit_cast(unsigned int, h);
}
__device__ __forceinline__ unsigned short hbits(float v) {
    return __builtin_bit_cast(unsigned short, (_Float16)v);
}

// ---------------- kernel 1: repack weights ----------------
// Encoder layouts as before; decoder weights pre-packed into exact MFMA
// 16x16x32 f16 B-fragment layout: lane l supplies B[k0+(l>>4)*8+i][n0+(l&15)].
// Gate col n = w*256 + u*4 + q  (wave w owns units w*64..; q=0..3 = i,f,g,o),
// original gate row grow = q*256 + (w*64+u).
__global__ __launch_bounds__(256) void prep_weights(
    const float* __restrict__ w_ih0, const float* __restrict__ w_hh0,
    const float* __restrict__ b_ih0, const float* __restrict__ b_hh0,
    const float* __restrict__ w_ih1, const float* __restrict__ w_hh1,
    const float* __restrict__ b_ih1, const float* __restrict__ b_hh1,
    float* __restrict__ ws) {
    int id = blockIdx.x * blockDim.x + threadIdx.x;   // grid covers 262144
    unsigned int* wsu = (unsigned int*)ws;
    // ---- encoder layouts ----
    {
        int g4 = id & 1023;
        int jj = g4 >> 2, q = g4 & 3;
        int grow = q * HID + jj;
        int p = id >> 10;
        int k0 = 2 * p;
        float v0, v1;
        if (k0 < 256) { v0 = w_ih1[grow * HID + k0];       v1 = w_ih1[grow * HID + k0 + 1]; }
        else          { v0 = w_hh1[grow * HID + k0 - 256]; v1 = w_hh1[grow * HID + k0 - 255]; }
        wsu[OFF_WCAT1H + id] = packh2(v0, v1);
        if (id < 131072) {
            wsu[OFF_WHH0H + id] = packh2(w_hh0[grow * HID + 2 * p], w_hh0[grow * HID + 2 * p + 1]);
        }
        if (id < 7168) {
            int f = id >> 10;
            ws[OFF_WIH0 + id] = w_ih0[grow * NLAG + f];
        }
        if (id < 1024) {
            ws[OFF_B0 + id] = b_ih0[grow] + b_hh0[grow];
            ws[OFF_B1 + id] = b_ih1[grow] + b_hh1[grow];
        }
    }
    // ---- decoder biases by MFMA col ----
    if (id < 2048) {
        int n = id & 1023;
        int w = n >> 8, u = (n >> 2) & 63, q = n & 3;
        int grow = q * HID + w * 64 + u;
        if (id < 1024) ws[OFF_BN0 + n] = b_ih0[grow] + b_hh0[grow];
        else           ws[OFF_BN1 + n] = b_ih1[grow] + b_hh1[grow];
    }
    // ---- F0 fragments: 9 ks (ks0 = lag block) ----
    if (id < 36864) {
        int ks = id / 4096, rem = id % 4096, nt = rem >> 6, l = rem & 63;
        int n = nt * 16 + (l & 15);
        int w = n >> 8, u = (n >> 2) & 63, q = n & 3;
        int grow = q * HID + w * 64 + u;
        int kbase = (l >> 4) * 8;
        unsigned short h8[8];
        #pragma unroll
        for (int i = 0; i < 8; ++i) {
            float v;
            if (ks == 0) { int k = kbase + i; v = (k < NLAG) ? w_ih0[grow * NLAG + k] : 0.0f; }
            else         { int kk = (ks - 1) * 32 + kbase + i; v = w_hh0[grow * HID + kk]; }
            h8[i] = hbits(v);
        }
        uint4 o;
        o.x = (unsigned int)h8[0] | ((unsigned int)h8[1] << 16);
        o.y = (unsigned int)h8[2] | ((unsigned int)h8[3] << 16);
        o.z = (unsigned int)h8[4] | ((unsigned int)h8[5] << 16);
        o.w = (unsigned int)h8[6] | ((unsigned int)h8[7] << 16);
        ((uint4*)(ws + OFF_F0))[id] = o;
    }
    // ---- F1 fragments: 16 ks (k<256 = h0 via w_ih1, k>=256 = h1 via w_hh1) ----
    if (id < 65536) {
        int ks = id >> 12, rem = id & 4095, nt = rem >> 6, l = rem & 63;
        int n = nt * 16 + (l & 15);
        int w = n >> 8, u = (n >> 2) & 63, q = n & 3;
        int grow = q * HID + w * 64 + u;
        int kbase = (l >> 4) * 8;
        unsigned short h8[8];
        #pragma unroll
        for (int i = 0; i < 8; ++i) {
            int kk = ks * 32 + kbase + i;
            float v = (kk < 256) ? w_ih1[grow * HID + kk] : w_hh1[grow * HID + kk - 256];
            h8[i] = hbits(v);
        }
        uint4 o;
        o.x = (unsigned int)h8[0] | ((unsigned int)h8[1] << 16);
        o.y = (unsigned int)h8[2] | ((unsigned int)h8[3] << 16);
        o.z = (unsigned int)h8[4] | ((unsigned int)h8[5] << 16);
        o.w = (unsigned int)h8[6] | ((unsigned int)h8[7] << 16);
        ((uint4*)(ws + OFF_F1))[id] = o;
    }
}

// ---------------- kernel 2: normalize + zero accumulators ----------------
__global__ __launch_bounds__(256) void prep_norm(const float* __restrict__ x,
                                                 float* __restrict__ ws) {
    const int b = blockIdx.x, j = threadIdx.x;
    const float* row = x + b * TLEN;
    float s = 0.0f, s2 = 0.0f;
    for (int t = j; t < WIN; t += 256) {
        float v = row[NLAG + t];
        s += v;
        s2 = fmaf(v, v, s2);
    }
    #pragma unroll
    for (int off = 32; off > 0; off >>= 1) {
        s  += __shfl_down(s, off, 64);
        s2 += __shfl_down(s2, off, 64);
    }
    __shared__ float rs[4], rs2[4];
    __shared__ float sh_loc, sh_scale;
    int wave = j >> 6, lane = j & 63;
    if (lane == 0) { rs[wave] = s; rs2[wave] = s2; }
    __syncthreads();
    if (j == 0) {
        float S = rs[0] + rs[1] + rs[2] + rs[3];
        float S2 = rs2[0] + rs2[1] + rs2[2] + rs2[3];
        float mean = S * (1.0f / WIN);
        float var = S2 * (1.0f / WIN) - mean * mean;
        float sd = sqrtf(fmaxf(var, 0.0f));
        if (sd < 1e-10f) sd = 1.0f;
        sh_loc = mean; sh_scale = sd;
        ws[OFF_LOC + b] = mean;
        ws[OFF_SCALE + b] = sd;
    }
    __syncthreads();
    float loc = sh_loc, inv = 1.0f / sh_scale;
    for (int t = j; t < TLEN; t += 256) {
        ws[OFF_SCALED + b * TLEN + t] = (row[t] - loc) * inv;
    }
    if (j < PRED) ws[OFF_ACC + b * PRED + j] = 0.0f;
}

// ---------------- kernel 3: encoder (512 sequential steps) ----------------
// 256 blocks x 256 threads, 1 row/block (all CUs active). Per-CU-L2-BW-bound:
// 1.57 MB fp16 weights streamed per step. 8-deep double-buffered prefetch.
__global__ __launch_bounds__(256) void encoder_kernel(const float* __restrict__ wsr,
                                                      float* __restrict__ wsw) {
    const int j = threadIdx.x;
    const int b = blockIdx.x;
    __shared__ unsigned int h0p[128], h1p[128];   // half2-packed h
    __shared__ float xs[8];
    float c0 = 0.0f, c1 = 0.0f;
    if (j < 128) { h0p[j] = 0u; h1p[j] = 0u; }

    const float4* wih0v = (const float4*)(wsr + OFF_WIH0);
    const uint4* W0 = (const uint4*)((const unsigned int*)wsr + OFF_WHH0H);
    const uint4* W1 = (const uint4*)((const unsigned int*)wsr + OFF_WCAT1H);
    const float4 bv0 = ((const float4*)(wsr + OFF_B0))[j];
    const float4 bv1 = ((const float4*)(wsr + OFF_B1))[j];
    const float* sc = wsr + OFF_SCALED + b * TLEN;
    __syncthreads();

    for (int t = 0; t < WIN; ++t) {
        if (j < NLAG) xs[j] = sc[t + 6 - j];
        __syncthreads();
        // ---- layer 0 ----
        float4 a = bv0;
        #pragma unroll
        for (int f = 0; f < NLAG; ++f) fma4(a, wih0v[f * 256 + j], xs[f]);
        {
            uint4 wbuf[2][8];
            #pragma unroll
            for (int u = 0; u < 8; ++u) wbuf[0][u] = W0[u * 256 + j];
            #pragma unroll 1
            for (int blk = 0; blk < 16; ++blk) {
                int cur = blk & 1;
                if (blk < 15) {
                    #pragma unroll
                    for (int u = 0; u < 8; ++u) wbuf[cur ^ 1][u] = W0[((blk + 1) * 8 + u) * 256 + j];
                }
                #pragma unroll
                for (int u = 0; u < 8; ++u) dot2x4(a, h0p[blk * 8 + u], wbuf[cur][u]);
            }
        }
        __syncthreads();
        c0 = sigm(a.y) * c0 + sigm(a.x) * ftanh(a.z);
        ((_Float16*)h0p)[j] = (_Float16)(sigm(a.w) * ftanh(c0));
        __syncthreads();
        // ---- layer 1 ----
        float4 g = bv1;
        {
            uint4 wbuf[2][8];
            #pragma unroll
            for (int u = 0; u < 8; ++u) wbuf[0][u] = W1[u * 256 + j];
            #pragma unroll 1
            for (int blk = 0; blk < 32; ++blk) {
                int cur = blk & 1;
                if (blk < 31) {
                    #pragma unroll
                    for (int u = 0; u < 8; ++u) wbuf[cur ^ 1][u] = W1[((blk + 1) * 8 + u) * 256 + j];
                }
                const unsigned int* hp = (blk < 16) ? h0p : h1p;
                int pb = (blk & 15) * 8;
                #pragma unroll
                for (int u = 0; u < 8; ++u) dot2x4(g, hp[pb + u], wbuf[cur][u]);
            }
        }
        __syncthreads();
        c1 = sigm(g.y) * c1 + sigm(g.x) * ftanh(g.z);
        ((_Float16*)h1p)[j] = (_Float16)(sigm(g.w) * ftanh(c1));
        __syncthreads();
    }
    wsw[OFF_EH0 + b * HID + j] = (float)((_Float16*)h0p)[j];
    wsw[OFF_EC0 + b * HID + j] = c0;
    wsw[OFF_EH1 + b * HID + j] = (float)((_Float16*)h1p)[j];
    wsw[OFF_EC1 + b * HID + j] = c1;
}

// ---------------- kernel 4: MFMA decoder ----------------
// 32 rows/block, 800 blocks. 4 waves, wave w owns gate cols [w*256,(w+1)*256)
// = 64 units x 4 gates interleaved (col = ulocal*4 + q). B-fragments straight
// from global (pre-packed); A (h-states) fp16 in LDS, 264-half row stride.
// D->LDS per-wave transpose gives each thread 4 contiguous gates per unit.
#define RDEC 32
__global__ __launch_bounds__(256, 2) void decoder_kernel(
    const float* __restrict__ wsr,
    const float* __restrict__ w_mu, const float* __restrict__ b_mu,
    const float* __restrict__ w_sigma, const float* __restrict__ b_sigma,
    const float* __restrict__ eps, float* __restrict__ wsw) {
    const int j = threadIdx.x, lane = j & 63, wv = j >> 6;
    const int gr0 = blockIdx.x * RDEC;
    const int m16 = lane & 15, q16 = lane >> 4;
    __shared__ _Float16 hA[2][RDEC][264];   // [layer][row][unit], pad to 264
    __shared__ _Float16 xlag[RDEC][32];     // lag A-tile (k 0..6 live, rest 0)
    __shared__ float scr[4][16][68];        // per-wave D transpose scratch

    const uint4* F0 = (const uint4*)(wsr + OFF_F0);
    const uint4* F1 = (const uint4*)(wsr + OFF_F1);
    const float* bn0 = wsr + OFF_BN0;
    const float* bn1 = wsr + OFF_BN1;

    float c0r[8][4], c1r[8][4];
    // ---- init states ----
    for (int r = 0; r < RDEC; ++r) {
        int b = (gr0 + r) / NS;
        hA[0][r][j] = (_Float16)wsr[OFF_EH0 + b * HID + j];
        hA[1][r][j] = (_Float16)wsr[OFF_EH1 + b * HID + j];
    }
    { int r = j >> 3, p = j & 7;
      hA[0][r][256 + p] = (_Float16)0.0f; hA[1][r][256 + p] = (_Float16)0.0f; }
    #pragma unroll
    for (int it = 0; it < 4; ++it) {
        int idx = j + 256 * it;
        int r = idx >> 5, k = idx & 31;
        int b = (gr0 + r) / NS;
        xlag[r][k] = (k < NLAG) ? (_Float16)wsr[OFF_SCALED + b * TLEN + WIN + 6 - k]
                                : (_Float16)0.0f;
    }
    #pragma unroll
    for (int Q = 0; Q < 4; ++Q)
        #pragma unroll
        for (int mt = 0; mt < 2; ++mt) {
            int t2 = Q * 2 + mt;
            int b = (gr0 + mt * 16 + m16) / NS;
            #pragma unroll
            for (int i = 0; i < 4; ++i) {
                int jg = wv * 64 + Q * 16 + q16 * 4 + i;
                c0r[t2][i] = wsr[OFF_EC0 + b * HID + jg];
                c1r[t2][i] = wsr[OFF_EC1 + b * HID + jg];
            }
        }
    __syncthreads();

    float* accg = wsw + OFF_ACC;
    for (int st = 0; st < PRED; ++st) {
        uint2 hnew[8];
        // ================= layer 0 =================
        #pragma unroll 1
        for (int Q = 0; Q < 4; ++Q) {
            f32x4 acc[2][4];
            #pragma unroll
            for (int t = 0; t < 4; ++t) {
                float bb = bn0[wv * 256 + Q * 64 + t * 16 + m16];
                acc[0][t] = (f32x4){bb, bb, bb, bb};
                acc[1][t] = acc[0][t];
            }
            #pragma unroll
            for (int ks = 0; ks < 9; ++ks) {
                uint4 bw[4];
                #pragma unroll
                for (int t = 0; t < 4; ++t)
                    bw[t] = F0[(ks * 64 + wv * 16 + Q * 4 + t) * 64 + lane];
                #pragma unroll
                for (int mt = 0; mt < 2; ++mt) {
                    const _Float16* ap = (ks == 0)
                        ? &xlag[mt * 16 + m16][q16 * 8]
                        : &hA[0][mt * 16 + m16][(ks - 1) * 32 + q16 * 8];
                    half8 av = *(const half8*)ap;
                    #pragma unroll
                    for (int t = 0; t < 4; ++t)
                        acc[mt][t] = __builtin_amdgcn_mfma_f32_16x16x32_f16(
                            av, __builtin_bit_cast(half8, bw[t]), acc[mt][t], 0, 0, 0);
                }
            }
            #pragma unroll
            for (int mt = 0; mt < 2; ++mt) {
                #pragma unroll
                for (int t = 0; t < 4; ++t)
                    #pragma unroll
                    for (int rg = 0; rg < 4; ++rg)
                        scr[wv][q16 * 4 + rg][t * 16 + m16] = acc[mt][t][rg];
                __builtin_amdgcn_wave_barrier();
                int t2 = Q * 2 + mt;
                float hv[4];
                #pragma unroll
                for (int i = 0; i < 4; ++i) {
                    float4 g = *(const float4*)&scr[wv][m16][(q16 * 4 + i) * 4];
                    float c = sigm(g.y) * c0r[t2][i] + sigm(g.x) * ftanh(g.z);
                    c0r[t2][i] = c;
                    hv[i] = sigm(g.w) * ftanh(c);
                }
                __builtin_amdgcn_wave_barrier();
                hnew[t2] = make_uint2(packh2(hv[0], hv[1]), packh2(hv[2], hv[3]));
            }
        }
        __syncthreads();   // all L0 reads of hA[0]/xlag done
        #pragma unroll
        for (int Q = 0; Q < 4; ++Q)
            #pragma unroll
            for (int mt = 0; mt < 2; ++mt)
                *(uint2*)&hA[0][mt * 16 + m16][wv * 64 + Q * 16 + q16 * 4] = hnew[Q * 2 + mt];
        __syncthreads();   // hA[0] now h0(t)
        // ================= layer 1 =================
        #pragma unroll 1
        for (int Q = 0; Q < 4; ++Q) {
            f32x4 acc[2][4];
            #pragma unroll
            for (int t = 0; t < 4; ++t) {
                float bb = bn1[wv * 256 + Q * 64 + t * 16 + m16];
                acc[0][t] = (f32x4){bb, bb, bb, bb};
                acc[1][t] = acc[0][t];
            }
            #pragma unroll
            for (int ks = 0; ks < 16; ++ks) {
                uint4 bw[4];
                #pragma unroll
                for (int t = 0; t < 4; ++t)
                    bw[t] = F1[(ks * 64 + wv * 16 + Q * 4 + t) * 64 + lane];
                #pragma unroll
                for (int mt = 0; mt < 2; ++mt) {
                    const _Float16* ap = (ks < 8)
                        ? &hA[0][mt * 16 + m16][ks * 32 + q16 * 8]
                        : &hA[1][mt * 16 + m16][(ks - 8) * 32 + q16 * 8];
                    half8 av = *(const half8*)ap;
                    #pragma unroll
                    for (int t = 0; t < 4; ++t)
                        acc[mt][t] = __builtin_amdgcn_mfma_f32_16x16x32_f16(
                            av, __builtin_bit_cast(half8, bw[t]), acc[mt][t], 0, 0, 0);
                }
            }
            #pragma unroll
            for (int mt = 0; mt < 2; ++mt) {
                #pragma unroll
                for (int t = 0; t < 4; ++t)
                    #pragma unroll
                    for (int rg = 0; rg < 4; ++rg)
                        scr[wv][q16 * 4 + rg][t * 16 + m16] = acc[mt][t][rg];
                __builtin_amdgcn_wave_barrier();
                int t2 = Q * 2 + mt;
                float hv[4];
                #pragma unroll
                for (int i = 0; i < 4; ++i) {
                    float4 g = *(const float4*)&scr[wv][m16][(q16 * 4 + i) * 4];
                    float c = sigm(g.y) * c1r[t2][i] + sigm(g.x) * ftanh(g.z);
                    c1r[t2][i] = c;
                    hv[i] = sigm(g.w) * ftanh(c);
                }
                __builtin_amdgcn_wave_barrier();
                hnew[t2] = make_uint2(packh2(hv[0], hv[1]), packh2(hv[2], hv[3]));
            }
        }
        __syncthreads();   // all L1 reads of hA done
        #pragma unroll
        for (int Q = 0; Q < 4; ++Q)
            #pragma unroll
            for (int mt = 0; mt < 2; ++mt)
                *(uint2*)&hA[1][mt * 16 + m16][wv * 64 + Q * 16 + q16 * 4] = hnew[Q * 2 + mt];
        __syncthreads();   // hA[1] now h1(t)
        // ================= mu / sigma / sample =================
        #pragma unroll 1
        for (int it = 0; it < 8; ++it) {
            int rr = wv + it * 4;
            uint2 hu = *(const uint2*)&hA[1][rr][lane * 4];
            h2_t p0 = __builtin_bit_cast(h2_t, hu.x);
            h2_t p1 = __builtin_bit_cast(h2_t, hu.y);
            float4 wm = *(const float4*)&w_mu[lane * 4];
            float4 wsg = *(const float4*)&w_sigma[lane * 4];
            float h0f = (float)p0.x, h1f = (float)p0.y, h2f = (float)p1.x, h3f = (float)p1.y;
            float sm = h0f * wm.x + h1f * wm.y + h2f * wm.z + h3f * wm.w;
            float ss = h0f * wsg.x + h1f * wsg.y + h2f * wsg.z + h3f * wsg.w;
            #pragma unroll
            for (int off = 32; off > 0; off >>= 1) {
                sm += __shfl_down(sm, off, 64);
                ss += __shfl_down(ss, off, 64);
            }
            if (lane == 0) {
                float mu = sm + b_mu[0];
                float sg = softplus(ss + b_sigma[0]);
                int gr = gr0 + rr;
                float smp = fmaf(sg, eps[st * GROWS + gr], mu);
                atomicAdd(&accg[(gr / NS) * PRED + st], smp);
                #pragma unroll
                for (int f = NLAG - 1; f >= 1; --f) xlag[rr][f] = xlag[rr][f - 1];
                xlag[rr][0] = (_Float16)smp;
            }
        }
        __syncthreads();   // xlag(t+1) visible
    }
}

// ---------------- kernel 5: finalize ----------------
__global__ __launch_bounds__(256) void finalize_kernel(const float* __restrict__ ws,
                                                       float* __restrict__ out) {
    int i = blockIdx.x * blockDim.x + threadIdx.x;
    if (i < BATCH * PRED) {
        int b = i / PRED;
        out[i] = ws[OFF_ACC + i] * (1.0f / NS) * ws[OFF_SCALE + b] + ws[OFF_LOC + b];
    }
}

// ---------------- launch ----------------
extern "C" void kernel_launch(void* const* d_in, const int* in_sizes, int n_in,
                              void* d_out, int out_size, void* d_ws, size_t ws_size,
                              hipStream_t stream) {
    const float* targets = (const float*)d_in[0];
    const float* w_ih0 = (const float*)d_in[1];
    const float* w_hh0 = (const float*)d_in[2];
    const float* b_ih0 = (const float*)d_in[3];
    const float* b_hh0 = (const float*)d_in[4];
    const float* w_ih1 = (const float*)d_in[5];
    const float* w_hh1 = (const float*)d_in[6];
    const float* b_ih1 = (const float*)d_in[7];
    const float* b_hh1 = (const float*)d_in[8];
    const float* w_mu = (const float*)d_in[9];
    const float* b_mu = (const float*)d_in[10];
    const float* w_sigma = (const float*)d_in[11];
    const float* b_sigma = (const float*)d_in[12];
    const float* eps = (const float*)d_in[13];
    float* ws = (float*)d_ws;
    float* out = (float*)d_out;

    hipLaunchKernelGGL(prep_weights, dim3(1024), dim3(256), 0, stream,
                       w_ih0, w_hh0, b_ih0, b_hh0, w_ih1, w_hh1, b_ih1, b_hh1, ws);
    hipLaunchKernelGGL(prep_norm, dim3(BATCH), dim3(256), 0, stream, targets, ws);
    hipLaunchKernelGGL(encoder_kernel, dim3(BATCH), dim3(256), 0, stream, ws, ws);
    hipLaunchKernelGGL(decoder_kernel, dim3(GROWS / RDEC), dim3(256), 0, stream,
                       ws, w_mu, b_mu, w_sigma, b_sigma, eps, ws);
    hipLaunchKernelGGL(finalize_kernel, dim3((BATCH * PRED + 255) / 256), dim3(256), 0,
                       stream, ws, out);
}

// Round 4
// 10743.139 us; speedup vs baseline: 5.2121x; 5.2121x over previous
//
#include <hip/hip_runtime.h>
#include <math.h>

// ---------------- problem constants ----------------
#define BATCH 256
#define TLEN  519          // W + MAXLAG
#define WIN   512
#define HID   256
#define PRED  24
#define NS    100
#define NLAG  7
#define GROWS (BATCH * NS) // 25600 decoder rows

// ---------------- workspace layout (float/uint offsets) ----------------
#define OFF_SCALED 0
#define OFF_LOC    132864
#define OFF_SCALE  133120
#define OFF_WIH0   133376   // fp32 [f][j][q], f<7  (encoder lag weights)
#define OFF_WHH0H  140544   // half2 [p][j][q], p<128 (encoder)
#define OFF_WCAT1H 271616   // half2 [p][j][q], p<256 (encoder, ih1|hh1)
#define OFF_B0     533760   // fp32 combined b_ih0+b_hh0, [j][q]
#define OFF_B1     534784
#define OFF_BN0    535808   // fp32 bias by MFMA col n (layer0)
#define OFF_BN1    536832
#define OFF_F0     537856   // fp16 B-fragments layer0: 9 ks x 64 nt x 64 lane x 8
#define OFF_F1     685312   // fp16 B-fragments layer1: 16 ks x 64 nt x 64 lane x 8
#define OFF_EH0    947456   // encoder final states fp32 [b][j]
#define OFF_EC0    1012992
#define OFF_EH1    1078528
#define OFF_EC1    1144064
#define OFF_ACC    1209600  // sample accumulators [b][p]
#define WS_FLOATS  1215744  // 4.86 MB

// ---------------- helpers ----------------
typedef _Float16 h2_t  __attribute__((ext_vector_type(2)));
typedef _Float16 half8 __attribute__((ext_vector_type(8)));
typedef float    f32x4 __attribute__((ext_vector_type(4)));

__device__ __forceinline__ float sigm(float x) { return 1.0f / (1.0f + __expf(-x)); }
__device__ __forceinline__ float ftanh(float x) {
    float e = __expf(2.0f * x);
    return 1.0f - 2.0f / (e + 1.0f);
}
__device__ __forceinline__ float softplus(float x) {
    return (x > 15.0f) ? x : log1pf(__expf(x));
}
__device__ __forceinline__ void fma4(float4& a, const float4 w, const float x) {
    a.x = fmaf(w.x, x, a.x);
    a.y = fmaf(w.y, x, a.y);
    a.z = fmaf(w.z, x, a.z);
    a.w = fmaf(w.w, x, a.w);
}
__device__ __forceinline__ float dot2(unsigned int h, unsigned int w, float acc) {
    return __builtin_amdgcn_fdot2(__builtin_bit_cast(h2_t, h),
                                  __builtin_bit_cast(h2_t, w), acc, false);
}
__device__ __forceinline__ void dot2x4(float4& a, const unsigned int h, const uint4 w) {
    a.x = dot2(h, w.x, a.x);
    a.y = dot2(h, w.y, a.y);
    a.z = dot2(h, w.z, a.z);
    a.w = dot2(h, w.w, a.w);
}
__device__ __forceinline__ unsigned int packh2(float a, float b) {
    h2_t h;
    h.x = (_Float16)a;
    h.y = (_Float16)b;
    return __builtin_bit_cast(unsigned int, h);
}
__device__ __forceinline__ unsigned short hbits(float v) {
    return __builtin_bit_cast(unsigned short, (_Float16)v);
}

// ---------------- kernel 1: repack weights ----------------
__global__ __launch_bounds__(256) void prep_weights(
    const float* __restrict__ w_ih0, const float* __restrict__ w_hh0,
    const float* __restrict__ b_ih0, const float* __restrict__ b_hh0,
    const float* __restrict__ w_ih1, const float* __restrict__ w_hh1,
    const float* __restrict__ b_ih1, const float* __restrict__ b_hh1,
    float* __restrict__ ws) {
    int id = blockIdx.x * blockDim.x + threadIdx.x;   // grid covers 262144
    unsigned int* wsu = (unsigned int*)ws;
    // ---- encoder layouts ----
    {
        int g4 = id & 1023;
        int jj = g4 >> 2, q = g4 & 3;
        int grow = q * HID + jj;
        int p = id >> 10;
        int k0 = 2 * p;
        float v0, v1;
        if (k0 < 256) { v0 = w_ih1[grow * HID + k0];       v1 = w_ih1[grow * HID + k0 + 1]; }
        else          { v0 = w_hh1[grow * HID + k0 - 256]; v1 = w_hh1[grow * HID + k0 - 255]; }
        wsu[OFF_WCAT1H + id] = packh2(v0, v1);
        if (id < 131072) {
            wsu[OFF_WHH0H + id] = packh2(w_hh0[grow * HID + 2 * p], w_hh0[grow * HID + 2 * p + 1]);
        }
        if (id < 7168) {
            int f = id >> 10;
            ws[OFF_WIH0 + id] = w_ih0[grow * NLAG + f];
        }
        if (id < 1024) {
            ws[OFF_B0 + id] = b_ih0[grow] + b_hh0[grow];
            ws[OFF_B1 + id] = b_ih1[grow] + b_hh1[grow];
        }
    }
    // ---- decoder biases by MFMA col ----
    if (id < 2048) {
        int n = id & 1023;
        int w = n >> 8, u = (n >> 2) & 63, q = n & 3;
        int grow = q * HID + w * 64 + u;
        if (id < 1024) ws[OFF_BN0 + n] = b_ih0[grow] + b_hh0[grow];
        else           ws[OFF_BN1 + n] = b_ih1[grow] + b_hh1[grow];
    }
    // ---- F0 fragments: 9 ks (ks0 = lag block) ----
    if (id < 36864) {
        int ks = id / 4096, rem = id % 4096, nt = rem >> 6, l = rem & 63;
        int n = nt * 16 + (l & 15);
        int w = n >> 8, u = (n >> 2) & 63, q = n & 3;
        int grow = q * HID + w * 64 + u;
        int kbase = (l >> 4) * 8;
        unsigned short h8[8];
        #pragma unroll
        for (int i = 0; i < 8; ++i) {
            float v;
            if (ks == 0) { int k = kbase + i; v = (k < NLAG) ? w_ih0[grow * NLAG + k] : 0.0f; }
            else         { int kk = (ks - 1) * 32 + kbase + i; v = w_hh0[grow * HID + kk]; }
            h8[i] = hbits(v);
        }
        uint4 o;
        o.x = (unsigned int)h8[0] | ((unsigned int)h8[1] << 16);
        o.y = (unsigned int)h8[2] | ((unsigned int)h8[3] << 16);
        o.z = (unsigned int)h8[4] | ((unsigned int)h8[5] << 16);
        o.w = (unsigned int)h8[6] | ((unsigned int)h8[7] << 16);
        ((uint4*)(ws + OFF_F0))[id] = o;
    }
    // ---- F1 fragments: 16 ks ----
    if (id < 65536) {
        int ks = id >> 12, rem = id & 4095, nt = rem >> 6, l = rem & 63;
        int n = nt * 16 + (l & 15);
        int w = n >> 8, u = (n >> 2) & 63, q = n & 3;
        int grow = q * HID + w * 64 + u;
        int kbase = (l >> 4) * 8;
        unsigned short h8[8];
        #pragma unroll
        for (int i = 0; i < 8; ++i) {
            int kk = ks * 32 + kbase + i;
            float v = (kk < 256) ? w_ih1[grow * HID + kk] : w_hh1[grow * HID + kk - 256];
            h8[i] = hbits(v);
        }
        uint4 o;
        o.x = (unsigned int)h8[0] | ((unsigned int)h8[1] << 16);
        o.y = (unsigned int)h8[2] | ((unsigned int)h8[3] << 16);
        o.z = (unsigned int)h8[4] | ((unsigned int)h8[5] << 16);
        o.w = (unsigned int)h8[6] | ((unsigned int)h8[7] << 16);
        ((uint4*)(ws + OFF_F1))[id] = o;
    }
}

// ---------------- kernel 2: normalize + zero accumulators ----------------
__global__ __launch_bounds__(256) void prep_norm(const float* __restrict__ x,
                                                 float* __restrict__ ws) {
    const int b = blockIdx.x, j = threadIdx.x;
    const float* row = x + b * TLEN;
    float s = 0.0f, s2 = 0.0f;
    for (int t = j; t < WIN; t += 256) {
        float v = row[NLAG + t];
        s += v;
        s2 = fmaf(v, v, s2);
    }
    #pragma unroll
    for (int off = 32; off > 0; off >>= 1) {
        s  += __shfl_down(s, off, 64);
        s2 += __shfl_down(s2, off, 64);
    }
    __shared__ float rs[4], rs2[4];
    __shared__ float sh_loc, sh_scale;
    int wave = j >> 6, lane = j & 63;
    if (lane == 0) { rs[wave] = s; rs2[wave] = s2; }
    __syncthreads();
    if (j == 0) {
        float S = rs[0] + rs[1] + rs[2] + rs[3];
        float S2 = rs2[0] + rs2[1] + rs2[2] + rs2[3];
        float mean = S * (1.0f / WIN);
        float var = S2 * (1.0f / WIN) - mean * mean;
        float sd = sqrtf(fmaxf(var, 0.0f));
        if (sd < 1e-10f) sd = 1.0f;
        sh_loc = mean; sh_scale = sd;
        ws[OFF_LOC + b] = mean;
        ws[OFF_SCALE + b] = sd;
    }
    __syncthreads();
    float loc = sh_loc, inv = 1.0f / sh_scale;
    for (int t = j; t < TLEN; t += 256) {
        ws[OFF_SCALED + b * TLEN + t] = (row[t] - loc) * inv;
    }
    if (j < PRED) ws[OFF_ACC + b * PRED + j] = 0.0f;
}

// ---------------- kernel 3: encoder (512 sequential steps) ----------------
// 128 blocks x 512 threads (8 waves), 2 rows/block. Thread tid = (unit j =
// tid&255, k-half kh = tid>>8). Each k-half accumulates its half of the
// hidden dot products straight from global (L2-resident weights); partials
// combine via LDS; unit threads (kh==0) apply gate activations. NO per-thread
// arrays -> nothing can spill (r3 lesson: 175 GB of scratch writebacks).
#define ENC_T 512
__global__ __launch_bounds__(ENC_T) void encoder_kernel(const float* __restrict__ wsr,
                                                        float* __restrict__ wsw) {
    const int tid = threadIdx.x;
    const int j  = tid & 255;      // unit
    const int kh = tid >> 8;       // k-half (0/1)
    const int bb = blockIdx.x;     // 0..127
    __shared__ unsigned int h0p[2][128], h1p[2][128];   // half2-packed h per row
    __shared__ float4 pgs[2][2][256];                   // [row][kh][unit]
    __shared__ float4 wlag[NLAG * 256];                 // lag weights (28 KB)
    __shared__ float xs[2][NLAG];
    float c0[2] = {0.0f, 0.0f}, c1[2] = {0.0f, 0.0f};

    for (int i = tid; i < NLAG * 256; i += ENC_T)
        wlag[i] = ((const float4*)(wsr + OFF_WIH0))[i];
    if (tid < 128) { h0p[0][tid] = 0u; h0p[1][tid] = 0u; h1p[0][tid] = 0u; h1p[1][tid] = 0u; }

    const uint4* W0 = (const uint4*)((const unsigned int*)wsr + OFF_WHH0H);
    const uint4* W1 = (const uint4*)((const unsigned int*)wsr + OFF_WCAT1H);
    float4 bv0, bv1;
    if (kh == 0) {
        bv0 = ((const float4*)(wsr + OFF_B0))[j];
        bv1 = ((const float4*)(wsr + OFF_B1))[j];
    }
    const float* sc0 = wsr + OFF_SCALED + (bb * 2 + 0) * TLEN;
    const float* sc1 = wsr + OFF_SCALED + (bb * 2 + 1) * TLEN;
    __syncthreads();

    for (int t = 0; t < WIN; ++t) {
        if (tid < 2 * NLAG) {
            int r = tid / NLAG, f = tid % NLAG;
            xs[r][f] = (r ? sc1 : sc0)[t + 6 - f];
        }
        // ---- L0 partials over this thread's k-half ----
        {
            float4 a0 = {0, 0, 0, 0}, a1 = {0, 0, 0, 0};
            const uint4* Wp = W0 + (kh * 64) * 256 + j;
            const unsigned int* hp0 = &h0p[0][kh * 64];
            const unsigned int* hp1 = &h0p[1][kh * 64];
            #pragma unroll 4
            for (int p = 0; p < 64; ++p) {
                uint4 w = Wp[p * 256];
                dot2x4(a0, hp0[p], w);
                dot2x4(a1, hp1[p], w);
            }
            pgs[0][kh][j] = a0;
            pgs[1][kh][j] = a1;
        }
        __syncthreads();   // [A] pgs + xs ready; all L0 reads of h0p done
        if (kh == 0) {
            #pragma unroll
            for (int r = 0; r < 2; ++r) {
                float4 a = bv0;
                #pragma unroll
                for (int f = 0; f < NLAG; ++f) fma4(a, wlag[f * 256 + j], xs[r][f]);
                float4 p0 = pgs[r][0][j], p1 = pgs[r][1][j];
                a.x += p0.x + p1.x; a.y += p0.y + p1.y;
                a.z += p0.z + p1.z; a.w += p0.w + p1.w;
                c0[r] = sigm(a.y) * c0[r] + sigm(a.x) * ftanh(a.z);
                ((_Float16*)&h0p[r][0])[j] = (_Float16)(sigm(a.w) * ftanh(c0[r]));
            }
        }
        __syncthreads();   // [B] h0p(t) visible
        // ---- L1 partials: p in [kh*128, kh*128+128) over cat(h0,h1) ----
        {
            float4 a0 = {0, 0, 0, 0}, a1 = {0, 0, 0, 0};
            const uint4* Wp = W1 + (kh * 128) * 256 + j;
            #pragma unroll 4
            for (int p = 0; p < 128; ++p) {
                int pk = kh * 128 + p;
                unsigned int ha = (pk < 128) ? h0p[0][pk] : h1p[0][pk - 128];
                unsigned int hb = (pk < 128) ? h0p[1][pk] : h1p[1][pk - 128];
                uint4 w = Wp[p * 256];
                dot2x4(a0, ha, w);
                dot2x4(a1, hb, w);
            }
            pgs[0][kh][j] = a0;
            pgs[1][kh][j] = a1;
        }
        __syncthreads();   // [C] pgs ready; all L1 reads of h1p done
        if (kh == 0) {
            #pragma unroll
            for (int r = 0; r < 2; ++r) {
                float4 g = bv1;
                float4 p0 = pgs[r][0][j], p1 = pgs[r][1][j];
                g.x += p0.x + p1.x; g.y += p0.y + p1.y;
                g.z += p0.z + p1.z; g.w += p0.w + p1.w;
                c1[r] = sigm(g.y) * c1[r] + sigm(g.x) * ftanh(g.z);
                ((_Float16*)&h1p[r][0])[j] = (_Float16)(sigm(g.w) * ftanh(c1[r]));
            }
        }
        __syncthreads();   // [D] h1p(t) visible; pgs safe to overwrite
    }
    if (kh == 0) {
        #pragma unroll
        for (int r = 0; r < 2; ++r) {
            int b = bb * 2 + r;
            wsw[OFF_EH0 + b * HID + j] = (float)((_Float16*)&h0p[r][0])[j];
            wsw[OFF_EC0 + b * HID + j] = c0[r];
            wsw[OFF_EH1 + b * HID + j] = (float)((_Float16*)&h1p[r][0])[j];
            wsw[OFF_EC1 + b * HID + j] = c1[r];
        }
    }
}

// ---------------- kernel 4: MFMA decoder ----------------
#define RDEC 32
__global__ __launch_bounds__(256, 2) void decoder_kernel(
    const float* __restrict__ wsr,
    const float* __restrict__ w_mu, const float* __restrict__ b_mu,
    const float* __restrict__ w_sigma, const float* __restrict__ b_sigma,
    const float* __restrict__ eps, float* __restrict__ wsw) {
    const int j = threadIdx.x, lane = j & 63, wv = j >> 6;
    const int gr0 = blockIdx.x * RDEC;
    const int m16 = lane & 15, q16 = lane >> 4;
    __shared__ _Float16 hA[2][RDEC][264];   // [layer][row][unit], pad to 264
    __shared__ _Float16 xlag[RDEC][32];     // lag A-tile (k 0..6 live, rest 0)
    __shared__ float scr[4][16][68];        // per-wave D transpose scratch

    const uint4* F0 = (const uint4*)(wsr + OFF_F0);
    const uint4* F1 = (const uint4*)(wsr + OFF_F1);
    const float* bn0 = wsr + OFF_BN0;
    const float* bn1 = wsr + OFF_BN1;

    float c0r[8][4], c1r[8][4];
    for (int r = 0; r < RDEC; ++r) {
        int b = (gr0 + r) / NS;
        hA[0][r][j] = (_Float16)wsr[OFF_EH0 + b * HID + j];
        hA[1][r][j] = (_Float16)wsr[OFF_EH1 + b * HID + j];
    }
    { int r = j >> 3, p = j & 7;
      hA[0][r][256 + p] = (_Float16)0.0f; hA[1][r][256 + p] = (_Float16)0.0f; }
    #pragma unroll
    for (int it = 0; it < 4; ++it) {
        int idx = j + 256 * it;
        int r = idx >> 5, k = idx & 31;
        int b = (gr0 + r) / NS;
        xlag[r][k] = (k < NLAG) ? (_Float16)wsr[OFF_SCALED + b * TLEN + WIN + 6 - k]
                                : (_Float16)0.0f;
    }
    #pragma unroll
    for (int Q = 0; Q < 4; ++Q)
        #pragma unroll
        for (int mt = 0; mt < 2; ++mt) {
            int t2 = Q * 2 + mt;
            int b = (gr0 + mt * 16 + m16) / NS;
            #pragma unroll
            for (int i = 0; i < 4; ++i) {
                int jg = wv * 64 + Q * 16 + q16 * 4 + i;
                c0r[t2][i] = wsr[OFF_EC0 + b * HID + jg];
                c1r[t2][i] = wsr[OFF_EC1 + b * HID + jg];
            }
        }
    __syncthreads();

    float* accg = wsw + OFF_ACC;
    for (int st = 0; st < PRED; ++st) {
        uint2 hnew[8];
        // ================= layer 0 =================
        #pragma unroll 1
        for (int Q = 0; Q < 4; ++Q) {
            f32x4 acc[2][4];
            #pragma unroll
            for (int t = 0; t < 4; ++t) {
                float bb = bn0[wv * 256 + Q * 64 + t * 16 + m16];
                acc[0][t] = (f32x4){bb, bb, bb, bb};
                acc[1][t] = acc[0][t];
            }
            #pragma unroll
            for (int ks = 0; ks < 9; ++ks) {
                uint4 bw[4];
                #pragma unroll
                for (int t = 0; t < 4; ++t)
                    bw[t] = F0[(ks * 64 + wv * 16 + Q * 4 + t) * 64 + lane];
                #pragma unroll
                for (int mt = 0; mt < 2; ++mt) {
                    const _Float16* ap = (ks == 0)
                        ? &xlag[mt * 16 + m16][q16 * 8]
                        : &hA[0][mt * 16 + m16][(ks - 1) * 32 + q16 * 8];
                    half8 av = *(const half8*)ap;
                    #pragma unroll
                    for (int t = 0; t < 4; ++t)
                        acc[mt][t] = __builtin_amdgcn_mfma_f32_16x16x32_f16(
                            av, __builtin_bit_cast(half8, bw[t]), acc[mt][t], 0, 0, 0);
                }
            }
            #pragma unroll
            for (int mt = 0; mt < 2; ++mt) {
                #pragma unroll
                for (int t = 0; t < 4; ++t)
                    #pragma unroll
                    for (int rg = 0; rg < 4; ++rg)
                        scr[wv][q16 * 4 + rg][t * 16 + m16] = acc[mt][t][rg];
                __builtin_amdgcn_wave_barrier();
                int t2 = Q * 2 + mt;
                float hv[4];
                #pragma unroll
                for (int i = 0; i < 4; ++i) {
                    float4 g = *(const float4*)&scr[wv][m16][(q16 * 4 + i) * 4];
                    float c = sigm(g.y) * c0r[t2][i] + sigm(g.x) * ftanh(g.z);
                    c0r[t2][i] = c;
                    hv[i] = sigm(g.w) * ftanh(c);
                }
                __builtin_amdgcn_wave_barrier();
                hnew[t2] = make_uint2(packh2(hv[0], hv[1]), packh2(hv[2], hv[3]));
            }
        }
        __syncthreads();   // all L0 reads of hA[0]/xlag done
        #pragma unroll
        for (int Q = 0; Q < 4; ++Q)
            #pragma unroll
            for (int mt = 0; mt < 2; ++mt)
                *(uint2*)&hA[0][mt * 16 + m16][wv * 64 + Q * 16 + q16 * 4] = hnew[Q * 2 + mt];
        __syncthreads();   // hA[0] now h0(t)
        // ================= layer 1 =================
        #pragma unroll 1
        for (int Q = 0; Q < 4; ++Q) {
            f32x4 acc[2][4];
            #pragma unroll
            for (int t = 0; t < 4; ++t) {
                float bb = bn1[wv * 256 + Q * 64 + t * 16 + m16];
                acc[0][t] = (f32x4){bb, bb, bb, bb};
                acc[1][t] = acc[0][t];
            }
            #pragma unroll
            for (int ks = 0; ks < 16; ++ks) {
                uint4 bw[4];
                #pragma unroll
                for (int t = 0; t < 4; ++t)
                    bw[t] = F1[(ks * 64 + wv * 16 + Q * 4 + t) * 64 + lane];
                #pragma unroll
                for (int mt = 0; mt < 2; ++mt) {
                    const _Float16* ap = (ks < 8)
                        ? &hA[0][mt * 16 + m16][ks * 32 + q16 * 8]
                        : &hA[1][mt * 16 + m16][(ks - 8) * 32 + q16 * 8];
                    half8 av = *(const half8*)ap;
                    #pragma unroll
                    for (int t = 0; t < 4; ++t)
                        acc[mt][t] = __builtin_amdgcn_mfma_f32_16x16x32_f16(
                            av, __builtin_bit_cast(half8, bw[t]), acc[mt][t], 0, 0, 0);
                }
            }
            #pragma unroll
            for (int mt = 0; mt < 2; ++mt) {
                #pragma unroll
                for (int t = 0; t < 4; ++t)
                    #pragma unroll
                    for (int rg = 0; rg < 4; ++rg)
                        scr[wv][q16 * 4 + rg][t * 16 + m16] = acc[mt][t][rg];
                __builtin_amdgcn_wave_barrier();
                int t2 = Q * 2 + mt;
                float hv[4];
                #pragma unroll
                for (int i = 0; i < 4; ++i) {
                    float4 g = *(const float4*)&scr[wv][m16][(q16 * 4 + i) * 4];
                    float c = sigm(g.y) * c1r[t2][i] + sigm(g.x) * ftanh(g.z);
                    c1r[t2][i] = c;
                    hv[i] = sigm(g.w) * ftanh(c);
                }
                __builtin_amdgcn_wave_barrier();
                hnew[t2] = make_uint2(packh2(hv[0], hv[1]), packh2(hv[2], hv[3]));
            }
        }
        __syncthreads();   // all L1 reads of hA done
        #pragma unroll
        for (int Q = 0; Q < 4; ++Q)
            #pragma unroll
            for (int mt = 0; mt < 2; ++mt)
                *(uint2*)&hA[1][mt * 16 + m16][wv * 64 + Q * 16 + q16 * 4] = hnew[Q * 2 + mt];
        __syncthreads();   // hA[1] now h1(t)
        // ================= mu / sigma / sample =================
        #pragma unroll 1
        for (int it = 0; it < 8; ++it) {
            int rr = wv + it * 4;
            uint2 hu = *(const uint2*)&hA[1][rr][lane * 4];
            h2_t p0 = __builtin_bit_cast(h2_t, hu.x);
            h2_t p1 = __builtin_bit_cast(h2_t, hu.y);
            float4 wm = *(const float4*)&w_mu[lane * 4];
            float4 wsg = *(const float4*)&w_sigma[lane * 4];
            float h0f = (float)p0.x, h1f = (float)p0.y, h2f = (float)p1.x, h3f = (float)p1.y;
            float sm = h0f * wm.x + h1f * wm.y + h2f * wm.z + h3f * wm.w;
            float ss = h0f * wsg.x + h1f * wsg.y + h2f * wsg.z + h3f * wsg.w;
            #pragma unroll
            for (int off = 32; off > 0; off >>= 1) {
                sm += __shfl_down(sm, off, 64);
                ss += __shfl_down(ss, off, 64);
            }
            if (lane == 0) {
                float mu = sm + b_mu[0];
                float sg = softplus(ss + b_sigma[0]);
                int gr = gr0 + rr;
                float smp = fmaf(sg, eps[st * GROWS + gr], mu);
                atomicAdd(&accg[(gr / NS) * PRED + st], smp);
                #pragma unroll
                for (int f = NLAG - 1; f >= 1; --f) xlag[rr][f] = xlag[rr][f - 1];
                xlag[rr][0] = (_Float16)smp;
            }
        }
        __syncthreads();   // xlag(t+1) visible
    }
}

// ---------------- kernel 5: finalize ----------------
__global__ __launch_bounds__(256) void finalize_kernel(const float* __restrict__ ws,
                                                       float* __restrict__ out) {
    int i = blockIdx.x * blockDim.x + threadIdx.x;
    if (i < BATCH * PRED) {
        int b = i / PRED;
        out[i] = ws[OFF_ACC + i] * (1.0f / NS) * ws[OFF_SCALE + b] + ws[OFF_LOC + b];
    }
}

// ---------------- launch ----------------
extern "C" void kernel_launch(void* const* d_in, const int* in_sizes, int n_in,
                              void* d_out, int out_size, void* d_ws, size_t ws_size,
                              hipStream_t stream) {
    const float* targets = (const float*)d_in[0];
    const float* w_ih0 = (const float*)d_in[1];
    const float* w_hh0 = (const float*)d_in[2];
    const float* b_ih0 = (const float*)d_in[3];
    const float* b_hh0 = (const float*)d_in[4];
    const float* w_ih1 = (const float*)d_in[5];
    const float* w_hh1 = (const float*)d_in[6];
    const float* b_ih1 = (const float*)d_in[7];
    const float* b_hh1 = (const float*)d_in[8];
    const float* w_mu = (const float*)d_in[9];
    const float* b_mu = (const float*)d_in[10];
    const float* w_sigma = (const float*)d_in[11];
    const float* b_sigma = (const float*)d_in[12];
    const float* eps = (const float*)d_in[13];
    float* ws = (float*)d_ws;
    float* out = (float*)d_out;

    hipLaunchKernelGGL(prep_weights, dim3(1024), dim3(256), 0, stream,
                       w_ih0, w_hh0, b_ih0, b_hh0, w_ih1, w_hh1, b_ih1, b_hh1, ws);
    hipLaunchKernelGGL(prep_norm, dim3(BATCH), dim3(256), 0, stream, targets, ws);
    hipLaunchKernelGGL(encoder_kernel, dim3(128), dim3(ENC_T), 0, stream, ws, ws);
    hipLaunchKernelGGL(decoder_kernel, dim3(GROWS / RDEC), dim3(256), 0, stream,
                       ws, w_mu, b_mu, w_sigma, b_sigma, eps, ws);
    hipLaunchKernelGGL(finalize_kernel, dim3((BATCH * PRED + 255) / 256), dim3(256), 0,
                       stream, ws, out);
}